// Round 1
// baseline (287.224 us; speedup 1.0000x reference)
//
#include <hip/hip_runtime.h>
#include <hip/hip_bf16.h>

#define B_  128
#define T_  30
#define N_  10000
#define M_  5000
#define K_  10
#define CHK_W_ 6
#define OBS_W_ 50
#define EPS_ 1e-6f
#define LOG2_ 0.69314718056f

// One block per (b,t) row. Stage tanh(0.5*llr) for the whole N-row in LDS,
// then gather-product per segment.  BCE identity:
//   bce(-2*atanh(p), y) = log2 - log(1 + s*p),  s = (y ? -1 : +1)
__global__ __launch_bounds__(256) void decode_loss_kernel(
    const float* __restrict__ all_llrs,   // [B,T,N]
    const int*   __restrict__ syndromes,  // [B,M]
    const int*   __restrict__ observables,// [B,K]
    const int*   __restrict__ chk_idx,    // [M*6]
    const int*   __restrict__ obs_idx,    // [K*50]
    float*       __restrict__ out)        // [1]
{
    __shared__ float tn[N_];     // 40000 B
    __shared__ float red[4];

    const int bt  = blockIdx.x;        // 0..B*T-1
    const int b   = bt / T_;
    const int tid = threadIdx.x;

    // ---- stage tanh(0.5*x) into LDS, vectorized ----
    const float4* row4 = (const float4*)(all_llrs + (size_t)bt * N_);
    float4* tn4 = (float4*)tn;
    for (int i = tid; i < N_/4; i += 256) {
        float4 v = row4[i];
        float4 r;
        // tanh(x/2) = 1 - 2/(e^x + 1)
        r.x = 1.f - 2.f / (__expf(v.x) + 1.f);
        r.y = 1.f - 2.f / (__expf(v.y) + 1.f);
        r.z = 1.f - 2.f / (__expf(v.z) + 1.f);
        r.w = 1.f - 2.f / (__expf(v.w) + 1.f);
        tn4[i] = r;
    }
    __syncthreads();

    // ---- check segments: M=5000, width 6 ----
    float acc1 = 0.f;
    const int* syn = syndromes + (size_t)b * M_;
    for (int m = tid; m < M_; m += 256) {
        const int* ci = chk_idx + m * CHK_W_;
        float p = tn[ci[0]] * tn[ci[1]] * tn[ci[2]]
                * tn[ci[3]] * tn[ci[4]] * tn[ci[5]];
        p = fminf(fmaxf(p, -1.f + EPS_), 1.f - EPS_);
        float sp = syn[m] ? -p : p;
        acc1 += LOG2_ - __logf(1.f + sp);
    }

    // ---- observable segments: K=10, width 50 (tiny) ----
    float acc2 = 0.f;
    const int* obs = observables + (size_t)b * K_;
    for (int k = tid; k < K_; k += 256) {
        const int* oi = obs_idx + k * OBS_W_;
        float p = 1.f;
        #pragma unroll 10
        for (int j = 0; j < OBS_W_; ++j) p *= tn[oi[j]];
        p = fminf(fmaxf(p, -1.f + EPS_), 1.f - EPS_);
        float sp = obs[k] ? -p : p;
        acc2 += LOG2_ - __logf(1.f + sp);
    }

    float acc = 0.5f * acc1 + 0.5f * acc2;   // BETA = 0.5

    // ---- block reduce: wave64 shuffle, then cross-wave via LDS ----
    #pragma unroll
    for (int off = 32; off > 0; off >>= 1)
        acc += __shfl_down(acc, off, 64);
    if ((tid & 63) == 0) red[tid >> 6] = acc;
    __syncthreads();
    if (tid == 0) {
        float s = red[0] + red[1] + red[2] + red[3];
        atomicAdd(out, s * (1.f / (B_ * T_)));
    }
}

extern "C" void kernel_launch(void* const* d_in, const int* in_sizes, int n_in,
                              void* d_out, int out_size, void* d_ws, size_t ws_size,
                              hipStream_t stream) {
    const float* all_llrs    = (const float*)d_in[0];
    const int*   syndromes   = (const int*)d_in[1];
    const int*   observables = (const int*)d_in[2];
    const int*   chk_idx     = (const int*)d_in[3];
    // d_in[4] = chk_seg (implicit: fixed width 6)
    const int*   obs_idx     = (const int*)d_in[5];
    // d_in[6] = obs_seg (implicit: fixed width 50)
    float* out = (float*)d_out;

    // d_out is poisoned before every timed launch — zero it ourselves.
    hipMemsetAsync(out, 0, sizeof(float) * out_size, stream);

    dim3 grid(B_ * T_);
    dim3 block(256);
    decode_loss_kernel<<<grid, block, 0, stream>>>(
        all_llrs, syndromes, observables, chk_idx, obs_idx, out);
}

// Round 2
// 282.564 us; speedup vs baseline: 1.0165x; 1.0165x over previous
//
#include <hip/hip_runtime.h>
#include <hip/hip_bf16.h>
#include <hip/hip_fp16.h>

#define B_  128
#define T_  30
#define N_  10000
#define M_  5000
#define K_  10
#define CHK_W_ 6
#define OBS_W_ 50
#define EPS_ 1e-6f
#define LOG2_ 0.69314718056f

// One block per (b,t) row. Stage tanh(0.5*llr) for the whole N-row in LDS as
// fp16 (20 KB -> 8 blocks/CU occupancy), then gather-product per segment.
// BCE identity:  bce(-2*atanh(p), y) = log2 - log(1 + s*p),  s = (y ? -1 : +1)
__global__ __launch_bounds__(256) void decode_loss_kernel(
    const float* __restrict__ all_llrs,   // [B,T,N]
    const int*   __restrict__ syndromes,  // [B,M]
    const int*   __restrict__ observables,// [B,K]
    const int*   __restrict__ chk_idx,    // [M*6]
    const int*   __restrict__ obs_idx,    // [K*50]
    float*       __restrict__ out)        // [1]
{
    __shared__ __half tn[N_];    // 20000 B
    __shared__ float red[4];

    const int bt  = blockIdx.x;        // 0..B*T-1
    const int b   = bt / T_;
    const int tid = threadIdx.x;

    // ---- stage tanh(0.5*x) into LDS (fp16), vectorized ----
    const float4* row4 = (const float4*)(all_llrs + (size_t)bt * N_);
    __half2* tn2 = (__half2*)tn;
    for (int i = tid; i < N_/4; i += 256) {
        float4 v = row4[i];
        // tanh(x/2) = 1 - 2/(e^x + 1)
        float r0 = 1.f - 2.f / (__expf(v.x) + 1.f);
        float r1 = 1.f - 2.f / (__expf(v.y) + 1.f);
        float r2 = 1.f - 2.f / (__expf(v.z) + 1.f);
        float r3 = 1.f - 2.f / (__expf(v.w) + 1.f);
        tn2[2*i]   = __floats2half2_rn(r0, r1);
        tn2[2*i+1] = __floats2half2_rn(r2, r3);
    }
    __syncthreads();

    // ---- check segments: M=5000, width 6, indices as 3x int2 ----
    float acc1 = 0.f;
    const int*  syn = syndromes + (size_t)b * M_;
    const int2* ci2 = (const int2*)chk_idx;
    #pragma unroll 4
    for (int i = 0; i < (M_ + 255) / 256; ++i) {
        const int m = tid + i * 256;
        if (m < M_) {
            int2 q0 = ci2[m*3+0];
            int2 q1 = ci2[m*3+1];
            int2 q2 = ci2[m*3+2];
            float p = __half2float(tn[q0.x]) * __half2float(tn[q0.y])
                    * __half2float(tn[q1.x]) * __half2float(tn[q1.y])
                    * __half2float(tn[q2.x]) * __half2float(tn[q2.y]);
            p = fminf(fmaxf(p, -1.f + EPS_), 1.f - EPS_);
            float sp = syn[m] ? -p : p;
            acc1 += LOG2_ - __logf(1.f + sp);
        }
    }

    // ---- observable segments: K=10, width 50 (tiny) ----
    float acc2 = 0.f;
    const int* obs = observables + (size_t)b * K_;
    for (int k = tid; k < K_; k += 256) {
        const int* oi = obs_idx + k * OBS_W_;
        float p = 1.f;
        #pragma unroll 10
        for (int j = 0; j < OBS_W_; ++j) p *= __half2float(tn[oi[j]]);
        p = fminf(fmaxf(p, -1.f + EPS_), 1.f - EPS_);
        float sp = obs[k] ? -p : p;
        acc2 += LOG2_ - __logf(1.f + sp);
    }

    float acc = 0.5f * acc1 + 0.5f * acc2;   // BETA = 0.5

    // ---- block reduce: wave64 shuffle, then cross-wave via LDS ----
    #pragma unroll
    for (int off = 32; off > 0; off >>= 1)
        acc += __shfl_down(acc, off, 64);
    if ((tid & 63) == 0) red[tid >> 6] = acc;
    __syncthreads();
    if (tid == 0) {
        float s = red[0] + red[1] + red[2] + red[3];
        atomicAdd(out, s * (1.f / (B_ * T_)));
    }
}

extern "C" void kernel_launch(void* const* d_in, const int* in_sizes, int n_in,
                              void* d_out, int out_size, void* d_ws, size_t ws_size,
                              hipStream_t stream) {
    const float* all_llrs    = (const float*)d_in[0];
    const int*   syndromes   = (const int*)d_in[1];
    const int*   observables = (const int*)d_in[2];
    const int*   chk_idx     = (const int*)d_in[3];
    // d_in[4] = chk_seg (implicit: fixed width 6)
    const int*   obs_idx     = (const int*)d_in[5];
    // d_in[6] = obs_seg (implicit: fixed width 50)
    float* out = (float*)d_out;

    // d_out is poisoned before every timed launch — zero it ourselves.
    hipMemsetAsync(out, 0, sizeof(float) * out_size, stream);

    dim3 grid(B_ * T_);
    dim3 block(256);
    decode_loss_kernel<<<grid, block, 0, stream>>>(
        all_llrs, syndromes, observables, chk_idx, obs_idx, out);
}